// Round 9
// baseline (811.146 us; speedup 1.0000x reference)
//
#include <hip/hip_runtime.h>
#include <math.h>

#define N_LOC 32768
#define CONTENT 512
#define ADDR_D 64
#define HID 1024
#define IN_D 256
#define OUT_D 10
#define OVERALL 576
#define GRU_IN 832
#define EPS_C 1e-7f
#define NSTEPS 8

#define NBLK_P 4096
#define NWAVE_P (NBLK_P * 4)     // 16384 waves; 2 rows/wave, hoisted loads
#define RCOLS (OVERALL + 1)      // 576 reading cols + 1 ssum col

__device__ __forceinline__ float wred(float v) {
    #pragma unroll
    for (int m = 32; m; m >>= 1) v += __shfl_xor(v, m, 64);
    return v;
}
__device__ __forceinline__ float sigm(float x) { return 1.0f / (1.0f + expf(-x)); }
__device__ __forceinline__ float dot4(float4 a, float4 b) {
    return a.x * b.x + a.y * b.y + a.z * b.z + a.w * b.w;
}

// ---------------- init: addr row norms^2, zero ema ----------------
__global__ __launch_bounds__(256) void k_init(const float* __restrict__ addrRows,
                                              float* __restrict__ addrsq,
                                              float* __restrict__ ema) {
    int tid = threadIdx.x, wid = tid >> 6, lane = tid & 63;
    int gid = blockIdx.x * 256 + tid;
    if (gid < N_LOC) ema[gid] = 0.0f;
    for (int i = blockIdx.x * 4 + wid; i < N_LOC; i += gridDim.x * 4) {
        float a = addrRows[(size_t)i * ADDR_D + lane];
        float sq = wred(a * a);
        if (lane == 0) addrsq[i] = sq;
    }
}

// ---------------- small matvecs: erase, cand, query, u_s.h, u_l.h ----------------
__global__ __launch_bounds__(256) void k_small(
    const float* __restrict__ W_e, const float* __restrict__ b_e,
    const float* __restrict__ W_ch, const float* __restrict__ W_ci, const float* __restrict__ b_c,
    const float* __restrict__ W_q, const float* __restrict__ b_q,
    const float* __restrict__ u_s, const float* __restrict__ u_l,
    const float* __restrict__ x, const float* __restrict__ h,
    float* __restrict__ erase, float* __restrict__ cand, float* __restrict__ query,
    float* __restrict__ slots_t, int doEC) {
    int tid = threadIdx.x, wid = tid >> 6, lane = tid & 63;
    int t = blockIdx.x * 4 + wid;
    const int base = doEC ? 2 * CONTENT : 0;
    const float4* h4 = (const float4*)h;
    const float4* x4 = (const float4*)x;
    if (doEC && t < CONTENT) {
        const float4* row = (const float4*)(W_e + (size_t)t * HID);
        float d = 0.0f;
        #pragma unroll
        for (int i = 0; i < 4; i++) d += dot4(row[lane + 64 * i], h4[lane + 64 * i]);
        d = wred(d);
        if (lane == 0) erase[t] = sigm(d + b_e[t]);
    } else if (doEC && t < 2 * CONTENT) {
        int r = t - CONTENT;
        const float4* row = (const float4*)(W_ch + (size_t)r * HID);
        float d = 0.0f;
        #pragma unroll
        for (int i = 0; i < 4; i++) d += dot4(row[lane + 64 * i], h4[lane + 64 * i]);
        const float4* row2 = (const float4*)(W_ci + (size_t)r * IN_D);
        d += dot4(row2[lane], x4[lane]);
        d = wred(d);
        if (lane == 0) cand[r] = fmaxf(d + b_c[r], 0.0f);
    } else if (t >= base && t < base + OVERALL) {
        int r = t - base;
        const float4* row = (const float4*)(W_q + (size_t)r * HID);
        float d = 0.0f;
        #pragma unroll
        for (int i = 0; i < 4; i++) d += dot4(row[lane + 64 * i], h4[lane + 64 * i]);
        d = wred(d);
        if (lane == 0) query[r] = d + b_q[r];
    } else if (t == base + OVERALL) {
        const float4* us4 = (const float4*)u_s;
        float d = 0.0f;
        #pragma unroll
        for (int i = 0; i < 4; i++) d += dot4(us4[lane + 64 * i], h4[lane + 64 * i]);
        d = wred(d);
        if (lane == 0) slots_t[1] = d;
    } else if (t == base + OVERALL + 1) {
        const float4* ul4 = (const float4*)u_l;
        float d = 0.0f;
        #pragma unroll
        for (int i = 0; i < 4; i++) d += dot4(ul4[lane + 64 * i], h4[lane + 64 * i]);
        d = wred(d);
        if (lane == 0) slots_t[2] = d;
    }
}

// ---------------- fused pass: lazy update + dots + sim + exp + reading partials ----------------
// 4096 blocks, 2 rows/wave, all loads hoisted (r4 body); plain part-stores (r7 reduction).
__global__ __launch_bounds__(256) void k_passAB(
    const float* __restrict__ memIn, float* __restrict__ memOut,
    int doUpdate, int doStore,
    const float* __restrict__ addrRows, const float* __restrict__ query,
    const float* __restrict__ erase, const float* __restrict__ cand,
    const float* __restrict__ addrsq, float* __restrict__ ema,
    float* __restrict__ exp_s, float* __restrict__ part,
    const float* __restrict__ slots_t, const float* __restrict__ ssum_prev,
    const float* __restrict__ b_sh, const float* __restrict__ b_lr) {
    int tid = threadIdx.x, wid = tid >> 6, lane = tid & 63;
    int gw = blockIdx.x * 4 + wid;
    const int i0 = gw;
    const int i1 = gw + NWAVE_P;   // 32768 = 2*16384

    __shared__ float lred[OVERALL];
    __shared__ float lsum4[4];
    for (int c = tid; c < OVERALL; c += 256) lred[c] = 0.0f;

    // ---- hoist all global loads ----
    const float4* r0p = (const float4*)(memIn + (size_t)i0 * CONTENT);
    const float4* r1p = (const float4*)(memIn + (size_t)i1 * CONTENT);
    float4 m00 = r0p[lane];
    float4 m01 = r0p[64 + lane];
    float4 m10 = r1p[lane];
    float4 m11 = r1p[64 + lane];
    float av0 = addrRows[(size_t)i0 * ADDR_D + lane];
    float av1 = addrRows[(size_t)i1 * ADDR_D + lane];
    float es_prev0 = doUpdate ? exp_s[i0] : 0.0f;
    float es_prev1 = doUpdate ? exp_s[i1] : 0.0f;
    float eo0 = ema[i0];
    float eo1 = ema[i1];
    float asq0 = addrsq[i0];
    float asq1 = addrsq[i1];

    const float4 q0 = *(const float4*)(query + 4 * lane);
    const float4 q1 = *(const float4*)(query + 256 + 4 * lane);
    const float qa = query[512 + lane];
    // qnorm^2 per-wave (redundant, cheap) instead of global atomics
    const float qq = wred(dot4(q0, q0) + dot4(q1, q1) + qa * qa);
    const float qnorm = sqrtf(qq);
    const float bs = slots_t[1] + b_sh[0];
    const float beta = (bs > 20.0f ? bs : log1pf(expf(bs))) + 1.0f;
    const float gamma = sigm(slots_t[2] + b_lr[0]);

    if (doUpdate) {
        const float4 e0 = *(const float4*)(erase + 4 * lane);
        const float4 e1 = *(const float4*)(erase + 256 + 4 * lane);
        const float4 c0 = *(const float4*)(cand + 4 * lane);
        const float4 c1 = *(const float4*)(cand + 256 + 4 * lane);
        const float invp = 1.0f / ssum_prev[0];
        const float wv0 = es_prev0 * invp;
        const float wv1 = es_prev1 * invp;
        m00.x = m00.x * (1.0f - wv0 * e0.x) + wv0 * c0.x;
        m00.y = m00.y * (1.0f - wv0 * e0.y) + wv0 * c0.y;
        m00.z = m00.z * (1.0f - wv0 * e0.z) + wv0 * c0.z;
        m00.w = m00.w * (1.0f - wv0 * e0.w) + wv0 * c0.w;
        m01.x = m01.x * (1.0f - wv0 * e1.x) + wv0 * c1.x;
        m01.y = m01.y * (1.0f - wv0 * e1.y) + wv0 * c1.y;
        m01.z = m01.z * (1.0f - wv0 * e1.z) + wv0 * c1.z;
        m01.w = m01.w * (1.0f - wv0 * e1.w) + wv0 * c1.w;
        m10.x = m10.x * (1.0f - wv1 * e0.x) + wv1 * c0.x;
        m10.y = m10.y * (1.0f - wv1 * e0.y) + wv1 * c0.y;
        m10.z = m10.z * (1.0f - wv1 * e0.z) + wv1 * c0.z;
        m10.w = m10.w * (1.0f - wv1 * e0.w) + wv1 * c0.w;
        m11.x = m11.x * (1.0f - wv1 * e1.x) + wv1 * c1.x;
        m11.y = m11.y * (1.0f - wv1 * e1.y) + wv1 * c1.y;
        m11.z = m11.z * (1.0f - wv1 * e1.z) + wv1 * c1.z;
        m11.w = m11.w * (1.0f - wv1 * e1.w) + wv1 * c1.w;
        if (doStore) {
            float4* o0 = (float4*)(memOut + (size_t)i0 * CONTENT);
            float4* o1 = (float4*)(memOut + (size_t)i1 * CONTENT);
            o0[lane] = m00;
            o0[64 + lane] = m01;
            o1[lane] = m10;
            o1[64 + lane] = m11;
        }
    }
    __syncthreads();

    // ---- dots + norms: 4 interleaved reduction chains ----
    float d0 = dot4(m00, q0) + dot4(m01, q1) + av0 * qa;
    float d1 = dot4(m10, q0) + dot4(m11, q1) + av1 * qa;
    float s0 = dot4(m00, m00) + dot4(m01, m01);
    float s1 = dot4(m10, m10) + dot4(m11, m11);
    #pragma unroll
    for (int m = 32; m; m >>= 1) {
        d0 += __shfl_xor(d0, m, 64);
        s0 += __shfl_xor(s0, m, 64);
        d1 += __shfl_xor(d1, m, 64);
        s1 += __shfl_xor(s1, m, 64);
    }
    float sim0 = beta * d0 / (sqrtf(s0 + asq0) * qnorm + EPS_C);
    float sim1 = beta * d1 / (sqrtf(s1 + asq1) * qnorm + EPS_C);
    float es0 = expf(sim0 - gamma * eo0);
    float es1 = expf(sim1 - gamma * eo1);
    if (lane == 0) {
        ema[i0] = 0.1f * eo0 + 0.9f * sim0;
        ema[i1] = 0.1f * eo1 + 0.9f * sim1;
        exp_s[i0] = es0;
        exp_s[i1] = es1;
    }

    // ---- reading numerator ----
    float4 racc0, racc1;
    racc0.x = es0 * m00.x + es1 * m10.x;
    racc0.y = es0 * m00.y + es1 * m10.y;
    racc0.z = es0 * m00.z + es1 * m10.z;
    racc0.w = es0 * m00.w + es1 * m10.w;
    racc1.x = es0 * m01.x + es1 * m11.x;
    racc1.y = es0 * m01.y + es1 * m11.y;
    racc1.z = es0 * m01.z + es1 * m11.z;
    racc1.w = es0 * m01.w + es1 * m11.w;
    float racca = es0 * av0 + es1 * av1;

    atomicAdd(&lred[4 * lane + 0], racc0.x);
    atomicAdd(&lred[4 * lane + 1], racc0.y);
    atomicAdd(&lred[4 * lane + 2], racc0.z);
    atomicAdd(&lred[4 * lane + 3], racc0.w);
    atomicAdd(&lred[256 + 4 * lane + 0], racc1.x);
    atomicAdd(&lred[256 + 4 * lane + 1], racc1.y);
    atomicAdd(&lred[256 + 4 * lane + 2], racc1.z);
    atomicAdd(&lred[256 + 4 * lane + 3], racc1.w);
    atomicAdd(&lred[512 + lane], racca);
    if (lane == 0) lsum4[wid] = es0 + es1;
    __syncthreads();

    // plain partial stores: part[c][block] (zero global atomics)
    const int b = blockIdx.x;
    for (int c = tid; c < OVERALL; c += 256)
        part[(size_t)c * NBLK_P + b] = lred[c];
    if (tid == 0)
        part[(size_t)OVERALL * NBLK_P + b] = lsum4[0] + lsum4[1] + lsum4[2] + lsum4[3];
}

// ---------------- reduce partials: one wave per column ----------------
__global__ __launch_bounds__(256) void k_red(const float* __restrict__ part,
                                             float* __restrict__ reading_t,
                                             float* __restrict__ ssum_t) {
    int tid = threadIdx.x, wid = tid >> 6, lane = tid & 63;
    int w = blockIdx.x * 4 + wid;
    if (w >= RCOLS) return;
    const float4* p4 = (const float4*)(part + (size_t)w * NBLK_P);
    float acc = 0.0f;
    #pragma unroll
    for (int i = 0; i < NBLK_P / 4 / 64; i++) {
        float4 v = p4[lane + 64 * i];
        acc += v.x + v.y + v.z + v.w;
    }
    acc = wred(acc);
    if (lane == 0) {
        if (w < OVERALL) reading_t[w] = acc;
        else ssum_t[0] = acc;
    }
}

// ---------------- GRU: one wave per hidden unit ----------------
__global__ __launch_bounds__(256) void k_gru(
    const float* __restrict__ W_ih, const float* __restrict__ W_hh,
    const float* __restrict__ b_ih, const float* __restrict__ b_hh,
    const float* __restrict__ x, const float* __restrict__ reading_t,
    const float* __restrict__ ssum_t,
    const float* __restrict__ hcur, float* __restrict__ hnew) {
    int tid = threadIdx.x, wid = tid >> 6, lane = tid & 63;
    __shared__ __align__(16) float rs[OVERALL];
    for (int c = tid; c < OVERALL; c += 256) rs[c] = reading_t[c];
    __syncthreads();

    const int k = blockIdx.x * 4 + wid;
    if (k >= HID) return;
    const float invs = 1.0f / ssum_t[0];
    const float4* x4 = (const float4*)x;
    const float4* r4 = (const float4*)rs;
    const float4* h4 = (const float4*)hcur;
    const float4* Wi0 = (const float4*)(W_ih + (size_t)k * GRU_IN);
    const float4* Wi1 = (const float4*)(W_ih + (size_t)(k + HID) * GRU_IN);
    const float4* Wi2 = (const float4*)(W_ih + (size_t)(k + 2 * HID) * GRU_IN);
    float gi0 = 0, gi1 = 0, gi2 = 0;
    {
        float4 v = x4[lane];
        gi0 += dot4(Wi0[lane], v); gi1 += dot4(Wi1[lane], v); gi2 += dot4(Wi2[lane], v);
    }
    #pragma unroll
    for (int i = 0; i < 2; i++) {
        float4 v = r4[lane + 64 * i];
        v.x *= invs; v.y *= invs; v.z *= invs; v.w *= invs;
        gi0 += dot4(Wi0[64 + lane + 64 * i], v);
        gi1 += dot4(Wi1[64 + lane + 64 * i], v);
        gi2 += dot4(Wi2[64 + lane + 64 * i], v);
    }
    {
        int j = 768 + lane;
        float v = rs[512 + lane] * invs;
        gi0 += W_ih[(size_t)k * GRU_IN + j] * v;
        gi1 += W_ih[(size_t)(k + HID) * GRU_IN + j] * v;
        gi2 += W_ih[(size_t)(k + 2 * HID) * GRU_IN + j] * v;
    }
    const float4* Wh0 = (const float4*)(W_hh + (size_t)k * HID);
    const float4* Wh1 = (const float4*)(W_hh + (size_t)(k + HID) * HID);
    const float4* Wh2 = (const float4*)(W_hh + (size_t)(k + 2 * HID) * HID);
    float gh0 = 0, gh1 = 0, gh2 = 0;
    #pragma unroll
    for (int i = 0; i < 4; i++) {
        float4 v = h4[lane + 64 * i];
        gh0 += dot4(Wh0[lane + 64 * i], v);
        gh1 += dot4(Wh1[lane + 64 * i], v);
        gh2 += dot4(Wh2[lane + 64 * i], v);
    }
    gi0 = wred(gi0); gi1 = wred(gi1); gi2 = wred(gi2);
    gh0 = wred(gh0); gh1 = wred(gh1); gh2 = wred(gh2);
    if (lane == 0) {
        float r = sigm(gi0 + b_ih[k] + gh0 + b_hh[k]);
        float z = sigm(gi1 + b_ih[HID + k] + gh1 + b_hh[HID + k]);
        float n = tanhf(gi2 + b_ih[2 * HID + k] + r * (gh2 + b_hh[2 * HID + k]));
        hnew[k] = (1.0f - z) * n + z * hcur[k];
    }
}

// ---------------- output: copy h, logits + log_softmax ----------------
__global__ __launch_bounds__(256) void k_out(const float* __restrict__ W_o,
                                             const float* __restrict__ b_o,
                                             const float* __restrict__ h,
                                             float* __restrict__ out) {
    int tid = threadIdx.x, wid = tid >> 6, lane = tid & 63;
    __shared__ float lg[OUT_D];
    for (int j = tid; j < HID; j += 256) out[j] = h[j];
    const float4* h4 = (const float4*)h;
    for (int u = wid; u < OUT_D; u += 4) {
        const float4* row = (const float4*)(W_o + (size_t)u * HID);
        float d = 0.0f;
        #pragma unroll
        for (int i = 0; i < 4; i++) d += dot4(row[lane + 64 * i], h4[lane + 64 * i]);
        d = wred(d);
        if (lane == 0) lg[u] = d + b_o[u];
    }
    __syncthreads();
    if (tid == 0) {
        float m = -1e30f;
        for (int u = 0; u < OUT_D; u++) m = fmaxf(m, lg[u]);
        float se = 0.0f;
        for (int u = 0; u < OUT_D; u++) se += expf(lg[u] - m);
        float lse = m + logf(se);
        for (int u = 0; u < OUT_D; u++) out[HID + u] = lg[u] - lse;
    }
}

extern "C" void kernel_launch(void* const* d_in, const int* in_sizes, int n_in,
                              void* d_out, int out_size, void* d_ws, size_t ws_size,
                              hipStream_t stream) {
    const float* x    = (const float*)d_in[0];
    const float* h0   = (const float*)d_in[1];
    const float* memC = (const float*)d_in[2];
    const float* addrR= (const float*)d_in[3];
    const float* W_q  = (const float*)d_in[4];
    const float* b_q  = (const float*)d_in[5];
    const float* u_s  = (const float*)d_in[6];
    const float* b_s  = (const float*)d_in[7];
    const float* u_l  = (const float*)d_in[8];
    const float* b_l  = (const float*)d_in[9];
    const float* W_e  = (const float*)d_in[10];
    const float* b_e  = (const float*)d_in[11];
    const float* W_ch = (const float*)d_in[12];
    const float* W_ci = (const float*)d_in[13];
    const float* b_c  = (const float*)d_in[14];
    const float* W_ih = (const float*)d_in[15];
    const float* W_hh = (const float*)d_in[16];
    const float* b_ih = (const float*)d_in[17];
    const float* b_hh = (const float*)d_in[18];
    const float* W_o  = (const float*)d_in[19];
    const float* b_o  = (const float*)d_in[20];

    const size_t MEMF = (size_t)N_LOC * CONTENT;
    const size_t SM_ADDRSQ = 0;
    const size_t SM_EXPS   = SM_ADDRSQ + N_LOC;
    const size_t SM_EMA    = SM_EXPS + N_LOC;
    const size_t SM_QUERY  = SM_EMA + N_LOC;
    const size_t SM_ER     = SM_QUERY + NSTEPS * OVERALL;
    const size_t SM_CAND   = SM_ER + NSTEPS * CONTENT;
    const size_t SM_H      = SM_CAND + NSTEPS * CONTENT;
    const size_t SM_SLOTS  = SM_H + (NSTEPS + 1) * HID;
    const size_t SM_SSUMR  = SM_SLOTS + NSTEPS * 8;
    const size_t SM_READ   = SM_SSUMR + 16;
    const size_t SM_PART   = SM_READ + NSTEPS * OVERALL;
    const size_t SM_TOT    = SM_PART + (size_t)RCOLS * NBLK_P;

    float* wsF = (float*)d_ws;
    bool useWs = ws_size >= (MEMF + SM_TOT) * sizeof(float);
    float* memBuf = useWs ? wsF : (float*)d_in[2];
    float* sb     = useWs ? (wsF + MEMF) : wsF;

    float* addrsq  = sb + SM_ADDRSQ;
    float* exp_s   = sb + SM_EXPS;
    float* ema     = sb + SM_EMA;
    float* query   = sb + SM_QUERY;
    float* erase   = sb + SM_ER;
    float* cand    = sb + SM_CAND;
    float* H       = sb + SM_H;
    float* slots   = sb + SM_SLOTS;
    float* ssum_red= sb + SM_SSUMR;
    float* reading = sb + SM_READ;
    float* part    = sb + SM_PART;

    k_init<<<512, 256, 0, stream>>>(addrR, addrsq, ema);
    k_small<<<(OVERALL + 2 + 3) / 4, 256, 0, stream>>>(
        W_e, b_e, W_ch, W_ci, b_c, W_q, b_q, u_s, u_l, x, h0,
        erase, cand, query, slots, 0);

    const float* hcur = h0;
    for (int t = 0; t < NSTEPS; t++) {
        float* slt = slots + t * 8;
        int doUpd = (t > 0) ? 1 : 0;
        int doStore = (t >= 1 && t <= NSTEPS - 2) ? 1 : 0;
        const float* memIn = (useWs && t <= 1) ? memC : memBuf;
        k_passAB<<<NBLK_P, 256, 0, stream>>>(
            memIn, memBuf, doUpd, doStore, addrR,
            query + t * OVERALL,
            erase + (t > 0 ? (t - 1) : 0) * CONTENT,
            cand + (t > 0 ? (t - 1) : 0) * CONTENT,
            addrsq, ema, exp_s, part,
            slt, (t > 0 ? ssum_red + (t - 1) : ssum_red), b_s, b_l);
        k_red<<<(RCOLS + 3) / 4, 256, 0, stream>>>(part, reading + t * OVERALL,
                                                  ssum_red + t);
        float* hn = H + (t + 1) * HID;
        k_gru<<<HID / 4, 256, 0, stream>>>(W_ih, W_hh, b_ih, b_hh, x,
                                           reading + t * OVERALL, ssum_red + t,
                                           hcur, hn);
        if (t < NSTEPS - 1) {
            k_small<<<(2 * CONTENT + OVERALL + 2 + 3) / 4, 256, 0, stream>>>(
                W_e, b_e, W_ch, W_ci, b_c, W_q, b_q, u_s, u_l, x, hn,
                erase + t * CONTENT, cand + t * CONTENT,
                query + (t + 1) * OVERALL, slots + (t + 1) * 8, 1);
        }
        hcur = hn;
    }
    k_out<<<1, 256, 0, stream>>>(W_o, b_o, hcur, (float*)d_out);
}

// Round 10
// 621.442 us; speedup vs baseline: 1.3053x; 1.3053x over previous
//
#include <hip/hip_runtime.h>
#include <math.h>

#define N_LOC 32768
#define CONTENT 512
#define ADDR_D 64
#define HID 1024
#define IN_D 256
#define OUT_D 10
#define OVERALL 576
#define GRU_IN 832
#define EPS_C 1e-7f
#define NSTEPS 8

#define NBLK_P 2048
#define NWAVE_P (NBLK_P * 4)     // 8192 waves; 4 rows/wave, all loads hoisted
#define RCOLS (OVERALL + 1)      // 576 reading cols + 1 ssum col
#define RP 580                   // padded row length (RP%4==0 -> 16B-aligned rows)
#define NRED 32                  // k_red blocks (64 part-rows each)

__device__ __forceinline__ float wred(float v) {
    #pragma unroll
    for (int m = 32; m; m >>= 1) v += __shfl_xor(v, m, 64);
    return v;
}
__device__ __forceinline__ float sigm(float x) { return 1.0f / (1.0f + expf(-x)); }
__device__ __forceinline__ float dot4(float4 a, float4 b) {
    return a.x * b.x + a.y * b.y + a.z * b.z + a.w * b.w;
}

// ---------------- init: addr row norms^2, zero ema ----------------
__global__ __launch_bounds__(256) void k_init(const float* __restrict__ addrRows,
                                              float* __restrict__ addrsq,
                                              float* __restrict__ ema) {
    int tid = threadIdx.x, wid = tid >> 6, lane = tid & 63;
    int gid = blockIdx.x * 256 + tid;
    if (gid < N_LOC) ema[gid] = 0.0f;
    for (int i = blockIdx.x * 4 + wid; i < N_LOC; i += gridDim.x * 4) {
        float a = addrRows[(size_t)i * ADDR_D + lane];
        float sq = wred(a * a);
        if (lane == 0) addrsq[i] = sq;
    }
}

// ---------------- small matvecs: erase, cand, query, u_s.h, u_l.h ----------------
__global__ __launch_bounds__(256) void k_small(
    const float* __restrict__ W_e, const float* __restrict__ b_e,
    const float* __restrict__ W_ch, const float* __restrict__ W_ci, const float* __restrict__ b_c,
    const float* __restrict__ W_q, const float* __restrict__ b_q,
    const float* __restrict__ u_s, const float* __restrict__ u_l,
    const float* __restrict__ x, const float* __restrict__ h,
    float* __restrict__ erase, float* __restrict__ cand, float* __restrict__ query,
    float* __restrict__ slots_t, int doEC) {
    int tid = threadIdx.x, wid = tid >> 6, lane = tid & 63;
    int t = blockIdx.x * 4 + wid;
    const int base = doEC ? 2 * CONTENT : 0;
    const float4* h4 = (const float4*)h;
    const float4* x4 = (const float4*)x;
    if (doEC && t < CONTENT) {
        const float4* row = (const float4*)(W_e + (size_t)t * HID);
        float d = 0.0f;
        #pragma unroll
        for (int i = 0; i < 4; i++) d += dot4(row[lane + 64 * i], h4[lane + 64 * i]);
        d = wred(d);
        if (lane == 0) erase[t] = sigm(d + b_e[t]);
    } else if (doEC && t < 2 * CONTENT) {
        int r = t - CONTENT;
        const float4* row = (const float4*)(W_ch + (size_t)r * HID);
        float d = 0.0f;
        #pragma unroll
        for (int i = 0; i < 4; i++) d += dot4(row[lane + 64 * i], h4[lane + 64 * i]);
        const float4* row2 = (const float4*)(W_ci + (size_t)r * IN_D);
        d += dot4(row2[lane], x4[lane]);
        d = wred(d);
        if (lane == 0) cand[r] = fmaxf(d + b_c[r], 0.0f);
    } else if (t >= base && t < base + OVERALL) {
        int r = t - base;
        const float4* row = (const float4*)(W_q + (size_t)r * HID);
        float d = 0.0f;
        #pragma unroll
        for (int i = 0; i < 4; i++) d += dot4(row[lane + 64 * i], h4[lane + 64 * i]);
        d = wred(d);
        if (lane == 0) query[r] = d + b_q[r];
    } else if (t == base + OVERALL) {
        const float4* us4 = (const float4*)u_s;
        float d = 0.0f;
        #pragma unroll
        for (int i = 0; i < 4; i++) d += dot4(us4[lane + 64 * i], h4[lane + 64 * i]);
        d = wred(d);
        if (lane == 0) slots_t[1] = d;
    } else if (t == base + OVERALL + 1) {
        const float4* ul4 = (const float4*)u_l;
        float d = 0.0f;
        #pragma unroll
        for (int i = 0; i < 4; i++) d += dot4(ul4[lane + 64 * i], h4[lane + 64 * i]);
        d = wred(d);
        if (lane == 0) slots_t[2] = d;
    }
}

// ---------------- fused pass: lazy update + dots + sim + exp + reading partials ----------------
// 2048 blocks; 4 rows/wave all hoisted; wave-private LDS rows (no atomics);
// coalesced row-major part stores.
__global__ __launch_bounds__(256) void k_passAB(
    const float* __restrict__ memIn, float* __restrict__ memOut,
    int doUpdate, int doStore,
    const float* __restrict__ addrRows, const float* __restrict__ query,
    const float* __restrict__ erase, const float* __restrict__ cand,
    const float* __restrict__ addrsq, float* __restrict__ ema,
    float* __restrict__ exp_s, float* __restrict__ part,
    const float* __restrict__ slots_t, const float* __restrict__ ssum_prev,
    const float* __restrict__ b_sh, const float* __restrict__ b_lr) {
    int tid = threadIdx.x, wid = tid >> 6, lane = tid & 63;
    int gw = blockIdx.x * 4 + wid;
    const int i0 = gw;
    const int i1 = gw + NWAVE_P;
    const int i2 = gw + 2 * NWAVE_P;
    const int i3 = gw + 3 * NWAVE_P;

    __shared__ __align__(16) float lredw[4][RP];  // wave-private partial rows

    // ---- hoist ALL global loads (4 mem rows = 9KB/wave in flight) ----
    const float4* r0p = (const float4*)(memIn + (size_t)i0 * CONTENT);
    const float4* r1p = (const float4*)(memIn + (size_t)i1 * CONTENT);
    const float4* r2p = (const float4*)(memIn + (size_t)i2 * CONTENT);
    const float4* r3p = (const float4*)(memIn + (size_t)i3 * CONTENT);
    float4 m00 = r0p[lane], m01 = r0p[64 + lane];
    float4 m10 = r1p[lane], m11 = r1p[64 + lane];
    float4 m20 = r2p[lane], m21 = r2p[64 + lane];
    float4 m30 = r3p[lane], m31 = r3p[64 + lane];
    float av0 = addrRows[(size_t)i0 * ADDR_D + lane];
    float av1 = addrRows[(size_t)i1 * ADDR_D + lane];
    float av2 = addrRows[(size_t)i2 * ADDR_D + lane];
    float av3 = addrRows[(size_t)i3 * ADDR_D + lane];
    float eo0 = ema[i0], eo1 = ema[i1], eo2 = ema[i2], eo3 = ema[i3];
    float asq0 = addrsq[i0], asq1 = addrsq[i1], asq2 = addrsq[i2], asq3 = addrsq[i3];

    const float4 q0 = *(const float4*)(query + 4 * lane);
    const float4 q1 = *(const float4*)(query + 256 + 4 * lane);
    const float qa = query[512 + lane];
    const float qq = wred(dot4(q0, q0) + dot4(q1, q1) + qa * qa);
    const float qnorm = sqrtf(qq);
    const float bs = slots_t[1] + b_sh[0];
    const float beta = (bs > 20.0f ? bs : log1pf(expf(bs))) + 1.0f;
    const float gamma = sigm(slots_t[2] + b_lr[0]);

    if (doUpdate) {
        const float4 e0 = *(const float4*)(erase + 4 * lane);
        const float4 e1 = *(const float4*)(erase + 256 + 4 * lane);
        const float4 c0 = *(const float4*)(cand + 4 * lane);
        const float4 c1 = *(const float4*)(cand + 256 + 4 * lane);
        const float invp = 1.0f / ssum_prev[0];
        const float wv0 = exp_s[i0] * invp;
        const float wv1 = exp_s[i1] * invp;
        const float wv2 = exp_s[i2] * invp;
        const float wv3 = exp_s[i3] * invp;
        #define UPD(m, e, c, wv) \
            m.x = m.x * (1.0f - wv * e.x) + wv * c.x; \
            m.y = m.y * (1.0f - wv * e.y) + wv * c.y; \
            m.z = m.z * (1.0f - wv * e.z) + wv * c.z; \
            m.w = m.w * (1.0f - wv * e.w) + wv * c.w;
        UPD(m00, e0, c0, wv0) UPD(m01, e1, c1, wv0)
        UPD(m10, e0, c0, wv1) UPD(m11, e1, c1, wv1)
        UPD(m20, e0, c0, wv2) UPD(m21, e1, c1, wv2)
        UPD(m30, e0, c0, wv3) UPD(m31, e1, c1, wv3)
        #undef UPD
        if (doStore) {
            float4* o0 = (float4*)(memOut + (size_t)i0 * CONTENT);
            float4* o1 = (float4*)(memOut + (size_t)i1 * CONTENT);
            float4* o2 = (float4*)(memOut + (size_t)i2 * CONTENT);
            float4* o3 = (float4*)(memOut + (size_t)i3 * CONTENT);
            o0[lane] = m00; o0[64 + lane] = m01;
            o1[lane] = m10; o1[64 + lane] = m11;
            o2[lane] = m20; o2[64 + lane] = m21;
            o3[lane] = m30; o3[64 + lane] = m31;
        }
    }

    // ---- dots + norms: 8 interleaved reduction chains ----
    float d0 = dot4(m00, q0) + dot4(m01, q1) + av0 * qa;
    float d1 = dot4(m10, q0) + dot4(m11, q1) + av1 * qa;
    float d2 = dot4(m20, q0) + dot4(m21, q1) + av2 * qa;
    float d3 = dot4(m30, q0) + dot4(m31, q1) + av3 * qa;
    float s0 = dot4(m00, m00) + dot4(m01, m01);
    float s1 = dot4(m10, m10) + dot4(m11, m11);
    float s2 = dot4(m20, m20) + dot4(m21, m21);
    float s3 = dot4(m30, m30) + dot4(m31, m31);
    #pragma unroll
    for (int m = 32; m; m >>= 1) {
        d0 += __shfl_xor(d0, m, 64); s0 += __shfl_xor(s0, m, 64);
        d1 += __shfl_xor(d1, m, 64); s1 += __shfl_xor(s1, m, 64);
        d2 += __shfl_xor(d2, m, 64); s2 += __shfl_xor(s2, m, 64);
        d3 += __shfl_xor(d3, m, 64); s3 += __shfl_xor(s3, m, 64);
    }
    float sim0 = beta * d0 / (sqrtf(s0 + asq0) * qnorm + EPS_C);
    float sim1 = beta * d1 / (sqrtf(s1 + asq1) * qnorm + EPS_C);
    float sim2 = beta * d2 / (sqrtf(s2 + asq2) * qnorm + EPS_C);
    float sim3 = beta * d3 / (sqrtf(s3 + asq3) * qnorm + EPS_C);
    float es0 = expf(sim0 - gamma * eo0);
    float es1 = expf(sim1 - gamma * eo1);
    float es2 = expf(sim2 - gamma * eo2);
    float es3 = expf(sim3 - gamma * eo3);
    if (lane == 0) {
        ema[i0] = 0.1f * eo0 + 0.9f * sim0;
        ema[i1] = 0.1f * eo1 + 0.9f * sim1;
        ema[i2] = 0.1f * eo2 + 0.9f * sim2;
        ema[i3] = 0.1f * eo3 + 0.9f * sim3;
        exp_s[i0] = es0; exp_s[i1] = es1; exp_s[i2] = es2; exp_s[i3] = es3;
    }

    // ---- wave-private reading numerator rows (plain LDS stores, no atomics) ----
    float* lw = lredw[wid];
    #pragma unroll
    for (int k = 0; k < 4; k++) {
        float a = (k == 0) ? (es0 * m00.x + es1 * m10.x + es2 * m20.x + es3 * m30.x)
                : (k == 1) ? (es0 * m00.y + es1 * m10.y + es2 * m20.y + es3 * m30.y)
                : (k == 2) ? (es0 * m00.z + es1 * m10.z + es2 * m20.z + es3 * m30.z)
                           : (es0 * m00.w + es1 * m10.w + es2 * m20.w + es3 * m30.w);
        lw[4 * lane + k] = a;
        float b2 = (k == 0) ? (es0 * m01.x + es1 * m11.x + es2 * m21.x + es3 * m31.x)
                 : (k == 1) ? (es0 * m01.y + es1 * m11.y + es2 * m21.y + es3 * m31.y)
                 : (k == 2) ? (es0 * m01.z + es1 * m11.z + es2 * m21.z + es3 * m31.z)
                            : (es0 * m01.w + es1 * m11.w + es2 * m21.w + es3 * m31.w);
        lw[256 + 4 * lane + k] = b2;
    }
    lw[512 + lane] = es0 * av0 + es1 * av1 + es2 * av2 + es3 * av3;
    if (lane == 0) lw[576] = es0 + es1 + es2 + es3;   // es are wave-uniform
    __syncthreads();

    // ---- combine 4 wave rows, store coalesced into part[b][c] ----
    float* pb = part + (size_t)blockIdx.x * RP;
    for (int c = tid; c < RCOLS; c += 256)
        pb[c] = lredw[0][c] + lredw[1][c] + lredw[2][c] + lredw[3][c];
}

// ---------------- reduce partials level 1: 32 blocks x 64 rows, fully coalesced ----------------
__global__ __launch_bounds__(256) void k_red(const float* __restrict__ part,
                                             float* __restrict__ partial2) {
    int tid = threadIdx.x;
    int g = blockIdx.x;
    float acc0 = 0.0f, acc1 = 0.0f, acc2 = 0.0f;
    const float* base = part + (size_t)g * 64 * RP;
    for (int r = 0; r < 64; r++) {
        const float* row = base + (size_t)r * RP;
        acc0 += row[tid];
        acc1 += row[256 + tid];
        if (tid < RCOLS - 512) acc2 += row[512 + tid];
    }
    partial2[(size_t)g * RP + tid] = acc0;
    partial2[(size_t)g * RP + 256 + tid] = acc1;
    if (tid < RCOLS - 512) partial2[(size_t)g * RP + 512 + tid] = acc2;
}

// ---------------- GRU: prologue reduces 32 partial2 rows; one wave per hidden unit ----------------
__global__ __launch_bounds__(256) void k_gru(
    const float* __restrict__ W_ih, const float* __restrict__ W_hh,
    const float* __restrict__ b_ih, const float* __restrict__ b_hh,
    const float* __restrict__ x, const float* __restrict__ partial2,
    float* __restrict__ ssum_red_t,
    const float* __restrict__ hcur, float* __restrict__ hnew) {
    int tid = threadIdx.x, wid = tid >> 6, lane = tid & 63;
    __shared__ __align__(16) float rs[OVERALL];
    __shared__ float ssum_sh;

    for (int c = tid; c < RCOLS; c += 256) {
        float s = 0.0f;
        #pragma unroll
        for (int g = 0; g < NRED; g++) s += partial2[(size_t)g * RP + c];
        if (c < OVERALL) rs[c] = s;
        else ssum_sh = s;
    }
    __syncthreads();
    if (blockIdx.x == 0 && tid == 0) ssum_red_t[0] = ssum_sh;

    const int k = blockIdx.x * 4 + wid;
    if (k >= HID) return;
    const float invs = 1.0f / ssum_sh;
    const float4* x4 = (const float4*)x;
    const float4* r4 = (const float4*)rs;
    const float4* h4 = (const float4*)hcur;
    const float4* Wi0 = (const float4*)(W_ih + (size_t)k * GRU_IN);
    const float4* Wi1 = (const float4*)(W_ih + (size_t)(k + HID) * GRU_IN);
    const float4* Wi2 = (const float4*)(W_ih + (size_t)(k + 2 * HID) * GRU_IN);
    float gi0 = 0, gi1 = 0, gi2 = 0;
    {
        float4 v = x4[lane];
        gi0 += dot4(Wi0[lane], v); gi1 += dot4(Wi1[lane], v); gi2 += dot4(Wi2[lane], v);
    }
    #pragma unroll
    for (int i = 0; i < 2; i++) {
        float4 v = r4[lane + 64 * i];
        v.x *= invs; v.y *= invs; v.z *= invs; v.w *= invs;
        gi0 += dot4(Wi0[64 + lane + 64 * i], v);
        gi1 += dot4(Wi1[64 + lane + 64 * i], v);
        gi2 += dot4(Wi2[64 + lane + 64 * i], v);
    }
    {
        int j = 768 + lane;
        float v = rs[512 + lane] * invs;
        gi0 += W_ih[(size_t)k * GRU_IN + j] * v;
        gi1 += W_ih[(size_t)(k + HID) * GRU_IN + j] * v;
        gi2 += W_ih[(size_t)(k + 2 * HID) * GRU_IN + j] * v;
    }
    const float4* Wh0 = (const float4*)(W_hh + (size_t)k * HID);
    const float4* Wh1 = (const float4*)(W_hh + (size_t)(k + HID) * HID);
    const float4* Wh2 = (const float4*)(W_hh + (size_t)(k + 2 * HID) * HID);
    float gh0 = 0, gh1 = 0, gh2 = 0;
    #pragma unroll
    for (int i = 0; i < 4; i++) {
        float4 v = h4[lane + 64 * i];
        gh0 += dot4(Wh0[lane + 64 * i], v);
        gh1 += dot4(Wh1[lane + 64 * i], v);
        gh2 += dot4(Wh2[lane + 64 * i], v);
    }
    gi0 = wred(gi0); gi1 = wred(gi1); gi2 = wred(gi2);
    gh0 = wred(gh0); gh1 = wred(gh1); gh2 = wred(gh2);
    if (lane == 0) {
        float r = sigm(gi0 + b_ih[k] + gh0 + b_hh[k]);
        float z = sigm(gi1 + b_ih[HID + k] + gh1 + b_hh[HID + k]);
        float n = tanhf(gi2 + b_ih[2 * HID + k] + r * (gh2 + b_hh[2 * HID + k]));
        hnew[k] = (1.0f - z) * n + z * hcur[k];
    }
}

// ---------------- output: copy h, logits + log_softmax ----------------
__global__ __launch_bounds__(256) void k_out(const float* __restrict__ W_o,
                                             const float* __restrict__ b_o,
                                             const float* __restrict__ h,
                                             float* __restrict__ out) {
    int tid = threadIdx.x, wid = tid >> 6, lane = tid & 63;
    __shared__ float lg[OUT_D];
    for (int j = tid; j < HID; j += 256) out[j] = h[j];
    const float4* h4 = (const float4*)h;
    for (int u = wid; u < OUT_D; u += 4) {
        const float4* row = (const float4*)(W_o + (size_t)u * HID);
        float d = 0.0f;
        #pragma unroll
        for (int i = 0; i < 4; i++) d += dot4(row[lane + 64 * i], h4[lane + 64 * i]);
        d = wred(d);
        if (lane == 0) lg[u] = d + b_o[u];
    }
    __syncthreads();
    if (tid == 0) {
        float m = -1e30f;
        for (int u = 0; u < OUT_D; u++) m = fmaxf(m, lg[u]);
        float se = 0.0f;
        for (int u = 0; u < OUT_D; u++) se += expf(lg[u] - m);
        float lse = m + logf(se);
        for (int u = 0; u < OUT_D; u++) out[HID + u] = lg[u] - lse;
    }
}

extern "C" void kernel_launch(void* const* d_in, const int* in_sizes, int n_in,
                              void* d_out, int out_size, void* d_ws, size_t ws_size,
                              hipStream_t stream) {
    const float* x    = (const float*)d_in[0];
    const float* h0   = (const float*)d_in[1];
    const float* memC = (const float*)d_in[2];
    const float* addrR= (const float*)d_in[3];
    const float* W_q  = (const float*)d_in[4];
    const float* b_q  = (const float*)d_in[5];
    const float* u_s  = (const float*)d_in[6];
    const float* b_s  = (const float*)d_in[7];
    const float* u_l  = (const float*)d_in[8];
    const float* b_l  = (const float*)d_in[9];
    const float* W_e  = (const float*)d_in[10];
    const float* b_e  = (const float*)d_in[11];
    const float* W_ch = (const float*)d_in[12];
    const float* W_ci = (const float*)d_in[13];
    const float* b_c  = (const float*)d_in[14];
    const float* W_ih = (const float*)d_in[15];
    const float* W_hh = (const float*)d_in[16];
    const float* b_ih = (const float*)d_in[17];
    const float* b_hh = (const float*)d_in[18];
    const float* W_o  = (const float*)d_in[19];
    const float* b_o  = (const float*)d_in[20];

    const size_t MEMF = (size_t)N_LOC * CONTENT;
    const size_t SM_ADDRSQ = 0;
    const size_t SM_EXPS   = SM_ADDRSQ + N_LOC;
    const size_t SM_EMA    = SM_EXPS + N_LOC;
    const size_t SM_QUERY  = SM_EMA + N_LOC;
    const size_t SM_ER     = SM_QUERY + NSTEPS * OVERALL;
    const size_t SM_CAND   = SM_ER + NSTEPS * CONTENT;
    const size_t SM_H      = SM_CAND + NSTEPS * CONTENT;
    const size_t SM_SLOTS  = SM_H + (NSTEPS + 1) * HID;
    const size_t SM_SSUMR  = SM_SLOTS + NSTEPS * 8;
    const size_t SM_PART   = SM_SSUMR + 16;                    // NBLK_P*RP
    const size_t SM_PART2  = SM_PART + (size_t)NBLK_P * RP;    // NRED*RP
    const size_t SM_TOT    = SM_PART2 + (size_t)NRED * RP;

    float* wsF = (float*)d_ws;
    bool useWs = ws_size >= (MEMF + SM_TOT) * sizeof(float);
    float* memBuf = useWs ? wsF : (float*)d_in[2];
    float* sb     = useWs ? (wsF + MEMF) : wsF;

    float* addrsq  = sb + SM_ADDRSQ;
    float* exp_s   = sb + SM_EXPS;
    float* ema     = sb + SM_EMA;
    float* query   = sb + SM_QUERY;
    float* erase   = sb + SM_ER;
    float* cand    = sb + SM_CAND;
    float* H       = sb + SM_H;
    float* slots   = sb + SM_SLOTS;
    float* ssum_red= sb + SM_SSUMR;
    float* part    = sb + SM_PART;
    float* partial2= sb + SM_PART2;

    k_init<<<512, 256, 0, stream>>>(addrR, addrsq, ema);
    k_small<<<(OVERALL + 2 + 3) / 4, 256, 0, stream>>>(
        W_e, b_e, W_ch, W_ci, b_c, W_q, b_q, u_s, u_l, x, h0,
        erase, cand, query, slots, 0);

    const float* hcur = h0;
    for (int t = 0; t < NSTEPS; t++) {
        float* slt = slots + t * 8;
        int doUpd = (t > 0) ? 1 : 0;
        int doStore = (t >= 1 && t <= NSTEPS - 2) ? 1 : 0;
        const float* memIn = (useWs && t <= 1) ? memC : memBuf;
        k_passAB<<<NBLK_P, 256, 0, stream>>>(
            memIn, memBuf, doUpd, doStore, addrR,
            query + t * OVERALL,
            erase + (t > 0 ? (t - 1) : 0) * CONTENT,
            cand + (t > 0 ? (t - 1) : 0) * CONTENT,
            addrsq, ema, exp_s, part,
            slt, (t > 0 ? ssum_red + (t - 1) : ssum_red), b_s, b_l);
        k_red<<<NRED, 256, 0, stream>>>(part, partial2);
        float* hn = H + (t + 1) * HID;
        k_gru<<<HID / 4, 256, 0, stream>>>(W_ih, W_hh, b_ih, b_hh, x,
                                           partial2, ssum_red + t, hcur, hn);
        if (t < NSTEPS - 1) {
            k_small<<<(2 * CONTENT + OVERALL + 2 + 3) / 4, 256, 0, stream>>>(
                W_e, b_e, W_ch, W_ci, b_c, W_q, b_q, u_s, u_l, x, hn,
                erase + t * CONTENT, cand + t * CONTENT,
                query + (t + 1) * OVERALL, slots + (t + 1) * 8, 1);
        }
        hcur = hn;
    }
    k_out<<<1, 256, 0, stream>>>(W_o, b_o, hcur, (float*)d_out);
}